// Round 9
// baseline (122.128 us; speedup 1.0000x reference)
//
#include <hip/hip_runtime.h>
#include <math.h>

// Problem constants: B=8, S=1024, D=128 (fp32 in/out)
#define NB 8
#define NS 1024
#define ND 128
#define NC 64     // chunks
#define NL 16     // steps per chunk

// workspace layout (float offsets)
#define OFF_K  0u
#define OFF_Q  1048576u
#define OFF_V  2097152u
#define OFF_E  3145728u
#define OFF_GA 4194304u
#define OFF_GE 4202496u
#define OFF_GT 4210688u
#define OFF_W  4218880u
#define OFF_C  4227072u
#define OFF_P  4235264u   // scan scratch

// chunked-scan scratch: packed A-quad (float4/entry) + B-pair (float2/entry)
#define PL_AQ  (OFF_P)                 // 4 * 65536 floats
#define PL_BP  (OFF_P + 262144u)       // 2 * 65536 floats
#define PL_WCA (OFF_P + 524288u)
#define PL_WCB (OFF_P + 524800u)
#define PL_WCD (OFF_P + 525312u)
// bf16 W^T hi+lo (3 mats x 128 cols x 128 k each), ushort
#define OFF_WT (OFF_P + 532480u)
#define WT_LO  49152u   // ushort offset of lo plane

typedef short bf16x8 __attribute__((ext_vector_type(8)));
typedef float f32x4  __attribute__((ext_vector_type(4)));

static __device__ __forceinline__ unsigned short f2bf(float f) {
    unsigned u = __builtin_bit_cast(unsigned, f);
    unsigned r = (u + 0x7FFFu + ((u >> 16) & 1u)) >> 16;   // RNE
    return (unsigned short)r;
}
static __device__ __forceinline__ float bf2f(unsigned short h) {
    unsigned u = ((unsigned)h) << 16;
    return __builtin_bit_cast(float, u);
}
static __device__ __forceinline__ void split2(float a, float b,
                                              unsigned& hi, unsigned& lo) {
    unsigned short ah = f2bf(a), bh = f2bf(b);
    float ar = a - bf2f(ah), br = b - bf2f(bh);
    hi = (unsigned)ah | ((unsigned)bh << 16);
    lo = (unsigned)f2bf(ar) | ((unsigned)f2bf(br) << 16);
}

// ---------------------------------------------------------------------------
// wtprep: W[k][c] fp32 -> wtg hi/lo planes [m][c][k] bf16 (transposed).
// Also zeroes the M/S output tail (atomics accumulate into it later).
// ---------------------------------------------------------------------------
__global__ __launch_bounds__(256) void wtprep_kernel(
    const float* __restrict__ Wk, const float* __restrict__ Wv,
    const float* __restrict__ Wq, unsigned short* __restrict__ wtg,
    float* __restrict__ outMS)
{
    const int m    = blockIdx.x >> 4;
    const int cgrp = blockIdx.x & 15;
    const int tid  = threadIdx.x;
    const int cl   = tid >> 5;
    const int h    = tid & 31;
    const int c    = cgrp * 8 + cl;
    const float* W = (m == 0) ? Wk : (m == 1) ? Wv : Wq;

    float f[4];
#pragma unroll
    for (int i = 0; i < 4; ++i)
        f[i] = W[(h * 4 + i) * ND + c];
    uint2 hi, lo;
    split2(f[0], f[1], hi.x, lo.x);
    split2(f[2], f[3], hi.y, lo.y);
    const unsigned base = (unsigned)m * 16384u + (unsigned)c * 128u + (unsigned)h * 4u;
    *(uint2*)&wtg[base]         = hi;
    *(uint2*)&wtg[WT_LO + base] = lo;

    // zero outMS: 65536 float4s over 48*256 = 12288 threads
    const int gidx = blockIdx.x * 256 + tid;
    const float4 z = {0.f, 0.f, 0.f, 0.f};
#pragma unroll
    for (int l = 0; l < 6; ++l) {
        int i4 = gidx + l * 12288;
        if (i4 < 65536) ((float4*)outMS)[i4] = z;
    }
}

// ---------------------------------------------------------------------------
// proj_mfma: one of {k,v,q} = x @ W via split-bf16 MFMA 16x16x32
// (3 MFMA terms: hi*hi + hi*lo + lo*hi -> ~fp32 precision).
// grid 1536 = 3 mats x 256 row-tiles(32) x 2 col-halves(64).
// Gate sidecar wave-parallel (2 lanes per dot, shfl_xor reduce).
// ---------------------------------------------------------------------------
__global__ __launch_bounds__(256) void proj_mfma(
    const float* __restrict__ x, const unsigned short* __restrict__ wtg,
    const float* __restrict__ Wg, const float* __restrict__ bg,
    float* __restrict__ Kb, float* __restrict__ Vb, float* __restrict__ Qb,
    float* __restrict__ ga, float* __restrict__ ge, float* __restrict__ gt)
{
    __shared__ unsigned short xs_hi[32 * 136];
    __shared__ unsigned short xs_lo[32 * 136];
    __shared__ unsigned short wt_hi[64 * 136];
    __shared__ unsigned short wt_lo[64 * 136];

    const int tid  = threadIdx.x;
    const int bid  = blockIdx.x;
    const int m    = bid >> 9;
    const int rt   = (bid >> 1) & 255;
    const int ch   = bid & 1;
    const int row0 = rt * 32;

    const float4* x4 = (const float4*)x;
#pragma unroll
    for (int l = 0; l < 4; ++l) {
        int idx = tid + l * 256;
        int r = idx >> 5, kq = idx & 31;
        float4 f = x4[(row0 + r) * 32 + kq];
        uint2 hi, lo;
        split2(f.x, f.y, hi.x, lo.x);
        split2(f.z, f.w, hi.y, lo.y);
        *(uint2*)&xs_hi[r * 136 + kq * 4] = hi;
        *(uint2*)&xs_lo[r * 136 + kq * 4] = lo;
    }
    const uint4* wh4 = (const uint4*)(wtg + m * 16384 + ch * 64 * 128);
    const uint4* wl4 = (const uint4*)(wtg + WT_LO + m * 16384 + ch * 64 * 128);
#pragma unroll
    for (int l = 0; l < 4; ++l) {
        int idx = tid + l * 256;
        int c = idx >> 4, u = idx & 15;
        *(uint4*)&wt_hi[c * 136 + u * 8] = wh4[c * 16 + u];
        *(uint4*)&wt_lo[c * 136 + u * 8] = wl4[c * 16 + u];
    }
    __syncthreads();

    const int wid  = tid >> 6;
    const int lane = tid & 63;
    const int rg   = wid >> 1;
    const int cg   = wid & 1;
    const int lrow = rg * 16 + (lane & 15);
    const int quad = lane >> 4;

    f32x4 acc[2];
    acc[0] = (f32x4){0.f, 0.f, 0.f, 0.f};
    acc[1] = (f32x4){0.f, 0.f, 0.f, 0.f};

#pragma unroll
    for (int kk = 0; kk < 4; ++kk) {
        bf16x8 ah = *(const bf16x8*)&xs_hi[lrow * 136 + kk * 32 + quad * 8];
        bf16x8 al = *(const bf16x8*)&xs_lo[lrow * 136 + kk * 32 + quad * 8];
#pragma unroll
        for (int ct = 0; ct < 2; ++ct) {
            int cl = cg * 32 + ct * 16 + (lane & 15);
            bf16x8 bh = *(const bf16x8*)&wt_hi[cl * 136 + kk * 32 + quad * 8];
            bf16x8 bl = *(const bf16x8*)&wt_lo[cl * 136 + kk * 32 + quad * 8];
            acc[ct] = __builtin_amdgcn_mfma_f32_16x16x32_bf16(ah, bh, acc[ct], 0, 0, 0);
            acc[ct] = __builtin_amdgcn_mfma_f32_16x16x32_bf16(ah, bl, acc[ct], 0, 0, 0);
            acc[ct] = __builtin_amdgcn_mfma_f32_16x16x32_bf16(al, bh, acc[ct], 0, 0, 0);
        }
    }

    float* dst = (m == 0) ? Kb : (m == 1) ? Vb : Qb;
#pragma unroll
    for (int ct = 0; ct < 2; ++ct) {
        int ocol = ch * 64 + cg * 32 + ct * 16 + (lane & 15);
#pragma unroll
        for (int r4 = 0; r4 < 4; ++r4) {
            int orow = row0 + rg * 16 + quad * 4 + r4;
            dst[orow * ND + ocol] = acc[ct][r4];
        }
    }

    // gate sidecar: 96 dots of length 128, 2 lanes per dot, float4 loads
    if (m == 0 && ch == 0 && tid < 192) {
        int p = tid >> 1;          // 0..95
        int h = tid & 1;
        int r = p / 3, j = p % 3;
        const float4* x4r = (const float4*)(x + (row0 + r) * ND + h * 64);
        float z = 0.f;
#pragma unroll
        for (int i4 = 0; i4 < 16; ++i4) {
            float4 f = x4r[i4];
            int i = h * 64 + i4 * 4;
            z = fmaf(f.x, Wg[(i    ) * 3 + j], z);
            z = fmaf(f.y, Wg[(i + 1) * 3 + j], z);
            z = fmaf(f.z, Wg[(i + 2) * 3 + j], z);
            z = fmaf(f.w, Wg[(i + 3) * 3 + j], z);
        }
        z += __shfl_xor(z, 1);
        if (h == 0) {
            z += bg[j];
            float gate = 1.0f / (1.0f + expf(-z));
            float* gd = (j == 0) ? ga : (j == 1) ? ge : gt;
            gd[row0 + r] = gate;
        }
    }
}

// ---------------------------------------------------------------------------
// Phase 1: per (b, chunk, d) compose the 16 per-step affine maps.
// A/B stored packed: float4 (A00,A01,A10,A11) + float2 (B0,B1) per entry.
// (round-8 proven; unchanged)
// ---------------------------------------------------------------------------
__global__ __launch_bounds__(128) void scan_phase1(
    const float* __restrict__ Kb, const float* __restrict__ Vb,
    const float* __restrict__ ga, const float* __restrict__ ge,
    const float* __restrict__ gt, float* __restrict__ ws)
{
    __shared__ float la[NL], le[NL], lt[NL];
    const int tid = threadIdx.x;
    const int b   = blockIdx.x >> 6;
    const int c   = blockIdx.x & 63;
    const int t0  = c * NL;
    const int g0  = b * NS + t0;

    if (tid < 16)       la[tid]      = ga[g0 + tid];
    else if (tid < 32)  le[tid - 16] = ge[g0 + tid - 16];
    else if (tid < 48)  lt[tid - 32] = gt[g0 + tid - 32];
    __syncthreads();

    const int d = tid;
    float A00 = 1.f, A01 = 0.f, A10 = 0.f, A11 = 1.f, B0 = 0.f, B1 = 0.f;
    int base = g0 * ND + d;
#pragma unroll
    for (int t = 0; t < NL; ++t) {
        float k = Kb[base], v = Vb[base];
        float a = la[t], e = le[t], th = lt[t];
        float tk = th * k;
        float gg = -tk * k;
        float h  = tk * v;
        float p  = (1.0f - a) + gg;
        float u0 = e * A10;
        float u1 = e * A11;
        float u2 = fmaf(e, B1, h);
        float n00 = fmaf(p, A00, u0), n10 = fmaf(gg, A00, u0);
        float n01 = fmaf(p, A01, u1), n11 = fmaf(gg, A01, u1);
        float nb0 = fmaf(p, B0, u2),  nb1 = fmaf(gg, B0, u2);
        A00 = n00; A01 = n01; A10 = n10; A11 = n11; B0 = nb0; B1 = nb1;
        base += ND;
    }
    const unsigned pidx = (unsigned)(b * NC + c) * ND + d;
    float4 aq = {A00, A01, A10, A11};
    float2 bp = {B0, B1};
    *(float4*)&ws[PL_AQ + 4u * pidx] = aq;
    *(float2*)&ws[PL_BP + 2u * pidx] = bp;

    if (tid == 0) {
        float al = 1.f, be = 1.f, de = 0.f;
#pragma unroll
        for (int t = NL - 1; t >= 0; --t) {
            float e1 = le[t];
            float o1 = 1.0f - la[t];
            de = fmaf(e1, de, o1 * be);
            al *= e1;
            be *= o1;
        }
        ws[PL_WCA + b * NC + c] = al;
        ws[PL_WCB + b * NC + c] = be;
        ws[PL_WCD + b * NC + c] = de;
    }
}

// ---------------------------------------------------------------------------
// Phase 3b: phase2 folded in. NEW: the w/c reverse chunk recurrence is now a
// wave-parallel SUFFIX SCAN in wave 0 (upper-triangular 2x2 affine
// M=[al,de;0,be]; 6-step Kogge-Stone over 64 chunk scalars, ~200cy) instead
// of tid0's serial avg-32-iteration dependent L2 load chain (~4-5us straggler
// per block since round 6). Entry-state rescan unchanged.
// ---------------------------------------------------------------------------
__global__ __launch_bounds__(128) void scan_phase3b(
    const float* __restrict__ Kb, const float* __restrict__ Vb,
    const float* __restrict__ Qb,
    const float* __restrict__ ga, const float* __restrict__ ge,
    const float* __restrict__ gt,
    float* __restrict__ out, float* __restrict__ errb,
    float* __restrict__ wb,  float* __restrict__ cb,
    float* __restrict__ ws)
{
    __shared__ float la[NL], le[NL], lt[NL];
    const int tid = threadIdx.x;
    const int b   = blockIdx.x >> 6;
    const int c   = 63 - (blockIdx.x & 63);   // longest-scan blocks first
    const int t0  = c * NL;
    const int g0  = b * NS + t0;

    if (tid < 16)       la[tid]      = ga[g0 + tid];
    else if (tid < 32)  le[tid - 16] = ge[g0 + tid - 16];
    else if (tid < 48)  lt[tid - 32] = gt[g0 + tid - 32];
    __syncthreads();

    // ---- wave-0 suffix scan of w/c chunk scalars ----
    // lane l holds M_l = [al_l, de_l; 0, be_l]; inclusive suffix
    // S_l = M_l ... M_63 via Kogge-Stone; exclusive E_c = S_{c+1};
    // Qp = E.a, P = E.b, A = E.a + E.d  (verified vs serial recurrence).
    float wQp = 1.f, wP = 1.f, wA = 1.f;
    if (tid < 64) {
        float sa = ws[PL_WCA + b * NC + tid];
        float sb = ws[PL_WCB + b * NC + tid];
        float sd = ws[PL_WCD + b * NC + tid];
#pragma unroll
        for (int off = 1; off < 64; off <<= 1) {
            float a2 = __shfl_down(sa, off);
            float d2 = __shfl_down(sd, off);
            float b2 = __shfl_down(sb, off);
            if (tid + off > 63) { a2 = 1.f; d2 = 0.f; b2 = 1.f; }
            float dn = fmaf(sa, d2, sd * b2);
            sa = sa * a2;
            sb = sb * b2;
            sd = dn;
        }
        float ae = __shfl_down(sa, 1);
        float dE = __shfl_down(sd, 1);
        float bE = __shfl_down(sb, 1);
        if (tid == 63) { ae = 1.f; dE = 0.f; bE = 1.f; }
        // broadcast chunk c's exclusive suffix to all lanes (tid0 consumes)
        float aC = __shfl(ae, c);
        float dC = __shfl(dE, c);
        float bC = __shfl(bE, c);
        wQp = aC; wP = bC; wA = aC + dC;
    }

    const int d = tid;

    // ---- entry state: forward scan of preceding chunks' affine maps ----
    float m = 0.f, s = 0.f;
    {
        const float4* aq = (const float4*)&ws[PL_AQ];
        const float2* bp = (const float2*)&ws[PL_BP];
        unsigned idx = (unsigned)(b * NC) * ND + d;
#pragma unroll 4
        for (int cc = 0; cc < c; ++cc) {
            float4 A  = aq[idx];
            float2 Bv = bp[idx];
            float nm = fmaf(A.x, m, fmaf(A.y, s, Bv.x));
            float ns = fmaf(A.z, m, fmaf(A.w, s, Bv.y));
            m = nm; s = ns;
            idx += ND;
        }
    }

    // ---- replay chunk c from its entry state ----
    int base = g0 * ND + d;
#pragma unroll
    for (int t = 0; t < NL; ++t) {
        float k = Kb[base], v = Vb[base], q = Qb[base];
        float a = la[t], e = le[t], th = lt[t];
        float err = fmaf(k, m, -v);
        out[base]  = q * m;
        errb[base] = err;
        float tk = th * k;
        float u  = fmaf(-(tk * k), m, tk * v);
        s = fmaf(e, s, u);
        m = fmaf(1.0f - a, m, s);
        base += ND;
    }

    // ---- w/c emission (scalars now from the wave scan, no load chain) ----
    if (tid == 0) {
        float Qp = wQp, P = wP, A = wA;
#pragma unroll
        for (int t = NL - 1; t >= 0; --t) {
            wb[g0 + t] = -lt[t] * Qp;
            cb[g0 + t] = -lt[t] * A;
            float e1 = le[t];
            float o1 = 1.0f - la[t];
            Qp *= e1;
            P  *= o1;
            A   = fmaf(e1, A, P);
        }
    }
}

// ---------------------------------------------------------------------------
// finalgemm: M/S final via fine split-K + atomicAdd. (round-0/6 proven tc16)
// grid 1024 = 8b x 16tc(64 t each) x 8rg(16 rows). 256 threads, 4 blocks/CU.
// ---------------------------------------------------------------------------
__global__ __launch_bounds__(256) void finalgemm_kernel(
    const float* __restrict__ Kb, const float* __restrict__ errb,
    const float* __restrict__ wb, const float* __restrict__ cb,
    float* __restrict__ outMS)
{
    __shared__ float ks[64 * 16];
    __shared__ float wcs[64 * 2];
    const int tid = threadIdx.x;
    const int bid = blockIdx.x;
    const int b   = bid >> 7;
    const int tc  = (bid >> 3) & 15;
    const int rg  = bid & 7;
    const int bt0 = b * NS + tc * 64;

    {
        int tl = tid >> 2, r4 = tid & 3;
        *(float4*)&ks[tl * 16 + r4 * 4] =
            *(const float4*)&Kb[(bt0 + tl) * ND + rg * 16 + r4 * 4];
    }
    if (tid < 64) {
        wcs[tid * 2]     = wb[bt0 + tid];
        wcs[tid * 2 + 1] = cb[bt0 + tid];
    }
    __syncthreads();

    const int j = tid & 127;
    const int h = tid >> 7;
    float accM[8], accS[8];
#pragma unroll
    for (int i = 0; i < 8; ++i) { accM[i] = 0.f; accS[i] = 0.f; }

    int ebase = bt0 * ND + j;
#pragma unroll 4
    for (int t = 0; t < 64; ++t) {
        float ej = errb[ebase];
        float2 wc = *(const float2*)&wcs[t * 2];
        float wej = wc.x * ej, cej = wc.y * ej;
        float4 k0 = *(const float4*)&ks[t * 16 + h * 8];
        float4 k1 = *(const float4*)&ks[t * 16 + h * 8 + 4];
        accS[0] = fmaf(k0.x, wej, accS[0]); accM[0] = fmaf(k0.x, cej, accM[0]);
        accS[1] = fmaf(k0.y, wej, accS[1]); accM[1] = fmaf(k0.y, cej, accM[1]);
        accS[2] = fmaf(k0.z, wej, accS[2]); accM[2] = fmaf(k0.z, cej, accM[2]);
        accS[3] = fmaf(k0.w, wej, accS[3]); accM[3] = fmaf(k0.w, cej, accM[3]);
        accS[4] = fmaf(k1.x, wej, accS[4]); accM[4] = fmaf(k1.x, cej, accM[4]);
        accS[5] = fmaf(k1.y, wej, accS[5]); accM[5] = fmaf(k1.y, cej, accM[5]);
        accS[6] = fmaf(k1.z, wej, accS[6]); accM[6] = fmaf(k1.z, cej, accM[6]);
        accS[7] = fmaf(k1.w, wej, accS[7]); accM[7] = fmaf(k1.w, cej, accM[7]);
        ebase += ND;
    }

    const int robase = rg * 16 + h * 8;
#pragma unroll
    for (int i = 0; i < 8; ++i) {
        int off = b * (ND * ND) + (robase + i) * ND + j;
        atomicAdd(&outMS[off], accM[i]);
        atomicAdd(&outMS[131072u + off], accS[i]);
    }
}

extern "C" void kernel_launch(void* const* d_in, const int* in_sizes, int n_in,
                              void* d_out, int out_size, void* d_ws, size_t ws_size,
                              hipStream_t stream) {
    const float* x  = (const float*)d_in[0];
    const float* Wk = (const float*)d_in[1];
    const float* Wv = (const float*)d_in[2];
    const float* Wq = (const float*)d_in[3];
    const float* Wg = (const float*)d_in[4];
    const float* bg = (const float*)d_in[5];
    float* out = (float*)d_out;
    float* ws  = (float*)d_ws;

    float* Kb  = ws + OFF_K;
    float* Qb  = ws + OFF_Q;
    float* Vb  = ws + OFF_V;
    float* Eb  = ws + OFF_E;
    float* ga  = ws + OFF_GA;
    float* ge  = ws + OFF_GE;
    float* gt  = ws + OFF_GT;
    float* wbf = ws + OFF_W;
    float* cbf = ws + OFF_C;
    float* outMS = out + 1048576u;
    unsigned short* wtg = (unsigned short*)(ws + OFF_WT);

    wtprep_kernel<<<48, 256, 0, stream>>>(Wk, Wv, Wq, wtg, outMS);
    proj_mfma<<<1536, 256, 0, stream>>>(x, wtg, Wg, bg,
                                        Kb, Vb, Qb, ga, ge, gt);
    scan_phase1<<<NB * NC, 128, 0, stream>>>(Kb, Vb, ga, ge, gt, ws);
    scan_phase3b<<<NB * NC, 128, 0, stream>>>(Kb, Vb, Qb, ga, ge, gt,
                                              out, Eb, wbf, cbf, ws);
    finalgemm_kernel<<<1024, 256, 0, stream>>>(Kb, Eb, wbf, cbf, outMS);
}

// Round 10
// 116.294 us; speedup vs baseline: 1.0502x; 1.0502x over previous
//
#include <hip/hip_runtime.h>
#include <math.h>

// Problem constants: B=8, S=1024, D=128 (fp32 in/out)
#define NB 8
#define NS 1024
#define ND 128
#define NC 64     // chunks
#define NL 16     // steps per chunk

// workspace layout (float offsets)
#define OFF_K  0u
#define OFF_Q  1048576u
#define OFF_V  2097152u
#define OFF_E  3145728u
#define OFF_GA 4194304u
#define OFF_GE 4202496u
#define OFF_GT 4210688u
#define OFF_W  4218880u
#define OFF_C  4227072u
#define OFF_P  4235264u   // scan scratch

// chunked-scan scratch: packed A-quad (float4/entry) + B-pair (float2/entry)
#define PL_AQ  (OFF_P)                 // 4 * 65536 floats
#define PL_BP  (OFF_P + 262144u)       // 2 * 65536 floats
#define PL_WCA (OFF_P + 524288u)
#define PL_WCB (OFF_P + 524800u)
#define PL_WCD (OFF_P + 525312u)
// bf16 W^T hi+lo (3 mats x 128 cols x 128 k each), ushort
#define OFF_WT (OFF_P + 532480u)
#define WT_LO  49152u   // ushort offset of lo plane

typedef short bf16x8 __attribute__((ext_vector_type(8)));
typedef float f32x4  __attribute__((ext_vector_type(4)));

static __device__ __forceinline__ unsigned short f2bf(float f) {
    unsigned u = __builtin_bit_cast(unsigned, f);
    unsigned r = (u + 0x7FFFu + ((u >> 16) & 1u)) >> 16;   // RNE
    return (unsigned short)r;
}
static __device__ __forceinline__ float bf2f(unsigned short h) {
    unsigned u = ((unsigned)h) << 16;
    return __builtin_bit_cast(float, u);
}
static __device__ __forceinline__ void split2(float a, float b,
                                              unsigned& hi, unsigned& lo) {
    unsigned short ah = f2bf(a), bh = f2bf(b);
    float ar = a - bf2f(ah), br = b - bf2f(bh);
    hi = (unsigned)ah | ((unsigned)bh << 16);
    lo = (unsigned)f2bf(ar) | ((unsigned)f2bf(br) << 16);
}

// ---------------------------------------------------------------------------
// wtprep: W[k][c] fp32 -> wtg hi/lo planes [m][c][k] bf16 (transposed).
// Also zeroes the M/S output tail (atomics accumulate into it later).
// Runs ONCE (48 blocks) so the strided W read is amortized — folding this
// into proj (1536 blocks) regressed +15us in round 7.
// ---------------------------------------------------------------------------
__global__ __launch_bounds__(256) void wtprep_kernel(
    const float* __restrict__ Wk, const float* __restrict__ Wv,
    const float* __restrict__ Wq, unsigned short* __restrict__ wtg,
    float* __restrict__ outMS)
{
    const int m    = blockIdx.x >> 4;
    const int cgrp = blockIdx.x & 15;
    const int tid  = threadIdx.x;
    const int cl   = tid >> 5;
    const int h    = tid & 31;
    const int c    = cgrp * 8 + cl;
    const float* W = (m == 0) ? Wk : (m == 1) ? Wv : Wq;

    float f[4];
#pragma unroll
    for (int i = 0; i < 4; ++i)
        f[i] = W[(h * 4 + i) * ND + c];
    uint2 hi, lo;
    split2(f[0], f[1], hi.x, lo.x);
    split2(f[2], f[3], hi.y, lo.y);
    const unsigned base = (unsigned)m * 16384u + (unsigned)c * 128u + (unsigned)h * 4u;
    *(uint2*)&wtg[base]         = hi;
    *(uint2*)&wtg[WT_LO + base] = lo;

    // zero outMS: 65536 float4s over 48*256 = 12288 threads
    const int gidx = blockIdx.x * 256 + tid;
    const float4 z = {0.f, 0.f, 0.f, 0.f};
#pragma unroll
    for (int l = 0; l < 6; ++l) {
        int i4 = gidx + l * 12288;
        if (i4 < 65536) ((float4*)outMS)[i4] = z;
    }
}

// ---------------------------------------------------------------------------
// proj_mfma: one of {k,v,q} = x @ W via split-bf16 MFMA 16x16x32
// (3 MFMA terms: hi*hi + hi*lo + lo*hi -> ~fp32 precision).
// grid 1536 = 3 mats x 256 row-tiles(32) x 2 col-halves(64).
// Gate sidecar wave-parallel (2 lanes per dot, shfl_xor reduce).
// ---------------------------------------------------------------------------
__global__ __launch_bounds__(256) void proj_mfma(
    const float* __restrict__ x, const unsigned short* __restrict__ wtg,
    const float* __restrict__ Wg, const float* __restrict__ bg,
    float* __restrict__ Kb, float* __restrict__ Vb, float* __restrict__ Qb,
    float* __restrict__ ga, float* __restrict__ ge, float* __restrict__ gt)
{
    __shared__ unsigned short xs_hi[32 * 136];
    __shared__ unsigned short xs_lo[32 * 136];
    __shared__ unsigned short wt_hi[64 * 136];
    __shared__ unsigned short wt_lo[64 * 136];

    const int tid  = threadIdx.x;
    const int bid  = blockIdx.x;
    const int m    = bid >> 9;
    const int rt   = (bid >> 1) & 255;
    const int ch   = bid & 1;
    const int row0 = rt * 32;

    const float4* x4 = (const float4*)x;
#pragma unroll
    for (int l = 0; l < 4; ++l) {
        int idx = tid + l * 256;
        int r = idx >> 5, kq = idx & 31;
        float4 f = x4[(row0 + r) * 32 + kq];
        uint2 hi, lo;
        split2(f.x, f.y, hi.x, lo.x);
        split2(f.z, f.w, hi.y, lo.y);
        *(uint2*)&xs_hi[r * 136 + kq * 4] = hi;
        *(uint2*)&xs_lo[r * 136 + kq * 4] = lo;
    }
    const uint4* wh4 = (const uint4*)(wtg + m * 16384 + ch * 64 * 128);
    const uint4* wl4 = (const uint4*)(wtg + WT_LO + m * 16384 + ch * 64 * 128);
#pragma unroll
    for (int l = 0; l < 4; ++l) {
        int idx = tid + l * 256;
        int c = idx >> 4, u = idx & 15;
        *(uint4*)&wt_hi[c * 136 + u * 8] = wh4[c * 16 + u];
        *(uint4*)&wt_lo[c * 136 + u * 8] = wl4[c * 16 + u];
    }
    __syncthreads();

    const int wid  = tid >> 6;
    const int lane = tid & 63;
    const int rg   = wid >> 1;
    const int cg   = wid & 1;
    const int lrow = rg * 16 + (lane & 15);
    const int quad = lane >> 4;

    f32x4 acc[2];
    acc[0] = (f32x4){0.f, 0.f, 0.f, 0.f};
    acc[1] = (f32x4){0.f, 0.f, 0.f, 0.f};

#pragma unroll
    for (int kk = 0; kk < 4; ++kk) {
        bf16x8 ah = *(const bf16x8*)&xs_hi[lrow * 136 + kk * 32 + quad * 8];
        bf16x8 al = *(const bf16x8*)&xs_lo[lrow * 136 + kk * 32 + quad * 8];
#pragma unroll
        for (int ct = 0; ct < 2; ++ct) {
            int cl = cg * 32 + ct * 16 + (lane & 15);
            bf16x8 bh = *(const bf16x8*)&wt_hi[cl * 136 + kk * 32 + quad * 8];
            bf16x8 bl = *(const bf16x8*)&wt_lo[cl * 136 + kk * 32 + quad * 8];
            acc[ct] = __builtin_amdgcn_mfma_f32_16x16x32_bf16(ah, bh, acc[ct], 0, 0, 0);
            acc[ct] = __builtin_amdgcn_mfma_f32_16x16x32_bf16(ah, bl, acc[ct], 0, 0, 0);
            acc[ct] = __builtin_amdgcn_mfma_f32_16x16x32_bf16(al, bh, acc[ct], 0, 0, 0);
        }
    }

    float* dst = (m == 0) ? Kb : (m == 1) ? Vb : Qb;
#pragma unroll
    for (int ct = 0; ct < 2; ++ct) {
        int ocol = ch * 64 + cg * 32 + ct * 16 + (lane & 15);
#pragma unroll
        for (int r4 = 0; r4 < 4; ++r4) {
            int orow = row0 + rg * 16 + quad * 4 + r4;
            dst[orow * ND + ocol] = acc[ct][r4];
        }
    }

    // gate sidecar: 96 dots of length 128, 2 lanes per dot, float4 loads
    if (m == 0 && ch == 0 && tid < 192) {
        int p = tid >> 1;          // 0..95
        int h = tid & 1;
        int r = p / 3, j = p % 3;
        const float4* x4r = (const float4*)(x + (row0 + r) * ND + h * 64);
        float z = 0.f;
#pragma unroll
        for (int i4 = 0; i4 < 16; ++i4) {
            float4 f = x4r[i4];
            int i = h * 64 + i4 * 4;
            z = fmaf(f.x, Wg[(i    ) * 3 + j], z);
            z = fmaf(f.y, Wg[(i + 1) * 3 + j], z);
            z = fmaf(f.z, Wg[(i + 2) * 3 + j], z);
            z = fmaf(f.w, Wg[(i + 3) * 3 + j], z);
        }
        z += __shfl_xor(z, 1);
        if (h == 0) {
            z += bg[j];
            float gate = 1.0f / (1.0f + expf(-z));
            float* gd = (j == 0) ? ga : (j == 1) ? ge : gt;
            gd[row0 + r] = gate;
        }
    }
}

// ---------------------------------------------------------------------------
// Phase 1: per (b, chunk, d) compose the 16 per-step affine maps.
// A/B stored packed: float4 (A00,A01,A10,A11) + float2 (B0,B1) per entry.
// ---------------------------------------------------------------------------
__global__ __launch_bounds__(128) void scan_phase1(
    const float* __restrict__ Kb, const float* __restrict__ Vb,
    const float* __restrict__ ga, const float* __restrict__ ge,
    const float* __restrict__ gt, float* __restrict__ ws)
{
    __shared__ float la[NL], le[NL], lt[NL];
    const int tid = threadIdx.x;
    const int b   = blockIdx.x >> 6;
    const int c   = blockIdx.x & 63;
    const int t0  = c * NL;
    const int g0  = b * NS + t0;

    if (tid < 16)       la[tid]      = ga[g0 + tid];
    else if (tid < 32)  le[tid - 16] = ge[g0 + tid - 16];
    else if (tid < 48)  lt[tid - 32] = gt[g0 + tid - 32];
    __syncthreads();

    const int d = tid;
    float A00 = 1.f, A01 = 0.f, A10 = 0.f, A11 = 1.f, B0 = 0.f, B1 = 0.f;
    int base = g0 * ND + d;
#pragma unroll
    for (int t = 0; t < NL; ++t) {
        float k = Kb[base], v = Vb[base];
        float a = la[t], e = le[t], th = lt[t];
        float tk = th * k;
        float gg = -tk * k;
        float h  = tk * v;
        float p  = (1.0f - a) + gg;
        float u0 = e * A10;
        float u1 = e * A11;
        float u2 = fmaf(e, B1, h);
        float n00 = fmaf(p, A00, u0), n10 = fmaf(gg, A00, u0);
        float n01 = fmaf(p, A01, u1), n11 = fmaf(gg, A01, u1);
        float nb0 = fmaf(p, B0, u2),  nb1 = fmaf(gg, B0, u2);
        A00 = n00; A01 = n01; A10 = n10; A11 = n11; B0 = nb0; B1 = nb1;
        base += ND;
    }
    const unsigned pidx = (unsigned)(b * NC + c) * ND + d;
    float4 aq = {A00, A01, A10, A11};
    float2 bp = {B0, B1};
    *(float4*)&ws[PL_AQ + 4u * pidx] = aq;
    *(float2*)&ws[PL_BP + 2u * pidx] = bp;

    if (tid == 0) {
        float al = 1.f, be = 1.f, de = 0.f;
#pragma unroll
        for (int t = NL - 1; t >= 0; --t) {
            float e1 = le[t];
            float o1 = 1.0f - la[t];
            de = fmaf(e1, de, o1 * be);
            al *= e1;
            be *= o1;
        }
        ws[PL_WCA + b * NC + c] = al;
        ws[PL_WCB + b * NC + c] = be;
        ws[PL_WCD + b * NC + c] = de;
    }
}

// ---------------------------------------------------------------------------
// Phase 3b: phase2 folded in. Each block (b,c) redundantly scans preceding
// chunks' packed affine maps (L2-resident) for its entry state; tid0
// serially composes the w/c reverse scalars (wave-parallel suffix-scan
// variant regressed −5.5us in round 9 — keep serial). c reversed so
// longest-scan blocks dispatch first.
// ---------------------------------------------------------------------------
__global__ __launch_bounds__(128) void scan_phase3b(
    const float* __restrict__ Kb, const float* __restrict__ Vb,
    const float* __restrict__ Qb,
    const float* __restrict__ ga, const float* __restrict__ ge,
    const float* __restrict__ gt,
    float* __restrict__ out, float* __restrict__ errb,
    float* __restrict__ wb,  float* __restrict__ cb,
    float* __restrict__ ws)
{
    __shared__ float la[NL], le[NL], lt[NL];
    const int tid = threadIdx.x;
    const int b   = blockIdx.x >> 6;
    const int c   = 63 - (blockIdx.x & 63);   // longest-scan blocks first
    const int t0  = c * NL;
    const int g0  = b * NS + t0;

    if (tid < 16)       la[tid]      = ga[g0 + tid];
    else if (tid < 32)  le[tid - 16] = ge[g0 + tid - 16];
    else if (tid < 48)  lt[tid - 32] = gt[g0 + tid - 32];
    __syncthreads();

    const int d = tid;

    // ---- entry state: forward scan of preceding chunks' affine maps ----
    float m = 0.f, s = 0.f;
    {
        const float4* aq = (const float4*)&ws[PL_AQ];
        const float2* bp = (const float2*)&ws[PL_BP];
        unsigned idx = (unsigned)(b * NC) * ND + d;
#pragma unroll 4
        for (int cc = 0; cc < c; ++cc) {
            float4 A  = aq[idx];
            float2 Bv = bp[idx];
            float nm = fmaf(A.x, m, fmaf(A.y, s, Bv.x));
            float ns = fmaf(A.z, m, fmaf(A.w, s, Bv.y));
            m = nm; s = ns;
            idx += ND;
        }
    }

    // ---- replay chunk c from its entry state ----
    int base = g0 * ND + d;
#pragma unroll
    for (int t = 0; t < NL; ++t) {
        float k = Kb[base], v = Vb[base], q = Qb[base];
        float a = la[t], e = le[t], th = lt[t];
        float err = fmaf(k, m, -v);
        out[base]  = q * m;
        errb[base] = err;
        float tk = th * k;
        float u  = fmaf(-(tk * k), m, tk * v);
        s = fmaf(e, s, u);
        m = fmaf(1.0f - a, m, s);
        base += ND;
    }

    // ---- w/c emission: reverse scalar scan of following chunks ----
    if (tid == 0) {
        float Qp = 1.f, P = 1.f, A = 1.f;
        for (int cc = NC - 1; cc > c; --cc) {
            float al = ws[PL_WCA + b * NC + cc];
            float be = ws[PL_WCB + b * NC + cc];
            float de = ws[PL_WCD + b * NC + cc];
            float nA = fmaf(al, A, de * P);
            Qp *= al; P *= be; A = nA;
        }
#pragma unroll
        for (int t = NL - 1; t >= 0; --t) {
            wb[g0 + t] = -lt[t] * Qp;
            cb[g0 + t] = -lt[t] * A;
            float e1 = le[t];
            float o1 = 1.0f - la[t];
            Qp *= e1;
            P  *= o1;
            A   = fmaf(e1, A, P);
        }
    }
}

// ---------------------------------------------------------------------------
// finalgemm: M/S final via fine split-K + atomicAdd. (proven tc16 config)
// grid 1024 = 8b x 16tc(64 t each) x 8rg(16 rows). 256 threads, 4 blocks/CU.
// ---------------------------------------------------------------------------
__global__ __launch_bounds__(256) void finalgemm_kernel(
    const float* __restrict__ Kb, const float* __restrict__ errb,
    const float* __restrict__ wb, const float* __restrict__ cb,
    float* __restrict__ outMS)
{
    __shared__ float ks[64 * 16];
    __shared__ float wcs[64 * 2];
    const int tid = threadIdx.x;
    const int bid = blockIdx.x;
    const int b   = bid >> 7;
    const int tc  = (bid >> 3) & 15;
    const int rg  = bid & 7;
    const int bt0 = b * NS + tc * 64;

    {
        int tl = tid >> 2, r4 = tid & 3;
        *(float4*)&ks[tl * 16 + r4 * 4] =
            *(const float4*)&Kb[(bt0 + tl) * ND + rg * 16 + r4 * 4];
    }
    if (tid < 64) {
        wcs[tid * 2]     = wb[bt0 + tid];
        wcs[tid * 2 + 1] = cb[bt0 + tid];
    }
    __syncthreads();

    const int j = tid & 127;
    const int h = tid >> 7;
    float accM[8], accS[8];
#pragma unroll
    for (int i = 0; i < 8; ++i) { accM[i] = 0.f; accS[i] = 0.f; }

    int ebase = bt0 * ND + j;
#pragma unroll 4
    for (int t = 0; t < 64; ++t) {
        float ej = errb[ebase];
        float2 wc = *(const float2*)&wcs[t * 2];
        float wej = wc.x * ej, cej = wc.y * ej;
        float4 k0 = *(const float4*)&ks[t * 16 + h * 8];
        float4 k1 = *(const float4*)&ks[t * 16 + h * 8 + 4];
        accS[0] = fmaf(k0.x, wej, accS[0]); accM[0] = fmaf(k0.x, cej, accM[0]);
        accS[1] = fmaf(k0.y, wej, accS[1]); accM[1] = fmaf(k0.y, cej, accM[1]);
        accS[2] = fmaf(k0.z, wej, accS[2]); accM[2] = fmaf(k0.z, cej, accM[2]);
        accS[3] = fmaf(k0.w, wej, accS[3]); accM[3] = fmaf(k0.w, cej, accM[3]);
        accS[4] = fmaf(k1.x, wej, accS[4]); accM[4] = fmaf(k1.x, cej, accM[4]);
        accS[5] = fmaf(k1.y, wej, accS[5]); accM[5] = fmaf(k1.y, cej, accM[5]);
        accS[6] = fmaf(k1.z, wej, accS[6]); accM[6] = fmaf(k1.z, cej, accM[6]);
        accS[7] = fmaf(k1.w, wej, accS[7]); accM[7] = fmaf(k1.w, cej, accM[7]);
        ebase += ND;
    }

    const int robase = rg * 16 + h * 8;
#pragma unroll
    for (int i = 0; i < 8; ++i) {
        int off = b * (ND * ND) + (robase + i) * ND + j;
        atomicAdd(&outMS[off], accM[i]);
        atomicAdd(&outMS[131072u + off], accS[i]);
    }
}

extern "C" void kernel_launch(void* const* d_in, const int* in_sizes, int n_in,
                              void* d_out, int out_size, void* d_ws, size_t ws_size,
                              hipStream_t stream) {
    const float* x  = (const float*)d_in[0];
    const float* Wk = (const float*)d_in[1];
    const float* Wv = (const float*)d_in[2];
    const float* Wq = (const float*)d_in[3];
    const float* Wg = (const float*)d_in[4];
    const float* bg = (const float*)d_in[5];
    float* out = (float*)d_out;
    float* ws  = (float*)d_ws;

    float* Kb  = ws + OFF_K;
    float* Qb  = ws + OFF_Q;
    float* Vb  = ws + OFF_V;
    float* Eb  = ws + OFF_E;
    float* ga  = ws + OFF_GA;
    float* ge  = ws + OFF_GE;
    float* gt  = ws + OFF_GT;
    float* wbf = ws + OFF_W;
    float* cbf = ws + OFF_C;
    float* outMS = out + 1048576u;
    unsigned short* wtg = (unsigned short*)(ws + OFF_WT);

    wtprep_kernel<<<48, 256, 0, stream>>>(Wk, Wv, Wq, wtg, outMS);
    proj_mfma<<<1536, 256, 0, stream>>>(x, wtg, Wg, bg,
                                        Kb, Vb, Qb, ga, ge, gt);
    scan_phase1<<<NB * NC, 128, 0, stream>>>(Kb, Vb, ga, ge, gt, ws);
    scan_phase3b<<<NB * NC, 128, 0, stream>>>(Kb, Vb, Qb, ga, ge, gt,
                                              out, Eb, wbf, cbf, ws);
    finalgemm_kernel<<<1024, 256, 0, stream>>>(Kb, Eb, wbf, cbf, outMS);
}